// Round 12
// baseline (153.403 us; speedup 1.0000x reference)
//
#include <hip/hip_runtime.h>
#include <math.h>

// Problem constants
constexpr int kT = 512;
constexpr int kB = 8;
constexpr int kD = 512;
constexpr int kM = 128;
constexpr int kNPairs = kT * kB;        // 4096 independent (t,b) pairs
constexpr int kGP = 8;                  // pairs per block (gates kernel)
constexpr int kGateThreads = 512;       // 8 waves: 4 matrices x 2 col-halves
constexpr int kThreads = 256;
constexpr int kRB = 64;                 // rows per stream block (2 blocks/pair)

typedef float f32x4 __attribute__((ext_vector_type(4)));
typedef float f32x2 __attribute__((ext_vector_type(2)));

// ---------------------------------------------------------------------------
// Kernel A: gates — EXACT round-10 winner. 512 blocks x 512 threads
// (8 waves), 8 pairs/block. Waves (2m, 2m+1) own matrix m; each wave
// covers 64 of 128 columns (lane -> 1 column, scalar FMA). 512 MB weight
// L2 traffic, 16 waves/CU, no cross-wave reduction.
// ---------------------------------------------------------------------------
__global__ __launch_bounds__(kGateThreads)
void mlstm_gates(const float* __restrict__ x,
                 const float* __restrict__ n_prev,
                 const float* __restrict__ Wq, const float* __restrict__ bq,
                 const float* __restrict__ Wk, const float* __restrict__ bk,
                 const float* __restrict__ Wv, const float* __restrict__ bv,
                 const float* __restrict__ wi, const float* __restrict__ bi,
                 const float* __restrict__ wf, const float* __restrict__ bf,
                 const float* __restrict__ Wo, const float* __restrict__ bo,
                 float* __restrict__ gq, float* __restrict__ gk,
                 float* __restrict__ gv, float* __restrict__ go,
                 float* __restrict__ gi, float* __restrict__ gf,
                 float* __restrict__ ginv,
                 float* __restrict__ out_n)
{
    __shared__ float sq[kGP][kM];     // q (for n-phase)
    __shared__ float sk[kGP][kM];     // k scaled by 1/sqrt(M)
    __shared__ float sif[kGP][2];     // i, f per pair

    const int tid = threadIdx.x;
    const int w   = tid >> 6;         // wave 0..7
    const int m   = w >> 1;           // matrix q,k,v,o
    const int ch  = w & 1;            // column half
    const int l   = tid & 63;         // lane
    const int c   = ch * 64 + l;      // column 0..127
    const int pair_base = blockIdx.x * kGP;
    const float* __restrict__ xblk = x + (size_t)pair_base * kD;

    // ---------------- main matvec: 4 matrices x 2 col-halves ----------------
    {
        const float* __restrict__ Wm = (m == 0) ? Wq : (m == 1) ? Wk : (m == 2) ? Wv : Wo;
        const float* __restrict__ bm = (m == 0) ? bq : (m == 1) ? bk : (m == 2) ? bv : bo;

        float acc[kGP];
        #pragma unroll
        for (int p = 0; p < kGP; ++p) acc[p] = 0.f;

        #pragma unroll 8
        for (int d = 0; d < kD; ++d) {
            const float wv = Wm[(size_t)d * kM + c];    // 256 B/wave, coalesced
            #pragma unroll
            for (int p = 0; p < kGP; ++p) {
                const float xv = xblk[p * kD + d];      // wave-uniform -> s_load
                acc[p] = fmaf(xv, wv, acc[p]);
            }
        }

        const float bc = bm[c];
        const float inv_sqrt_m = 0.08838834764831845f;  // 1/sqrt(128)
        float* __restrict__ gm = (m == 0) ? gq : (m == 1) ? gk : (m == 2) ? gv : go;

        #pragma unroll
        for (int p = 0; p < kGP; ++p) {
            float v = acc[p] + bc;
            if (m == 1) v *= inv_sqrt_m;
            if (m == 3) v = 1.f / (1.f + expf(-v));
            gm[(size_t)(pair_base + p) * kM + c] = v;
            if (m == 0) sq[p][c] = v;
            if (m == 1) sk[p][c] = v;
        }
    }

    // ---------------- i/f gates: wave w handles pair w ----------------------
    {
        const int p = w;                  // pair 0..7
        float ip = 0.f, fp = 0.f;
        #pragma unroll
        for (int dd = 0; dd < kD / 64; ++dd) {
            const int d = l + 64 * dd;
            const float xv = xblk[p * kD + d];
            ip += xv * wi[d];
            fp += xv * wf[d];
        }
        #pragma unroll
        for (int msk = 32; msk >= 1; msk >>= 1) {
            ip += __shfl_xor(ip, msk, 64);
            fp += __shfl_xor(fp, msk, 64);
        }
        if (l == 0) {
            sif[p][0] = expf(ip + bi[0]);
            sif[p][1] = 1.f / (1.f + expf(-(fp + bf[0])));
        }
    }
    __syncthreads();

    // ---------------- n update + normalizer ---------------------------------
    if (tid < 32 * kGP) {
        const int p = tid >> 5;         // pair 0..7 (32 threads per pair)
        const int s = tid & 31;
        const size_t pi = (size_t)(pair_base + p);
        const float iv = sif[p][0];
        const float fv = sif[p][1];

        const float4 np4 = *reinterpret_cast<const float4*>(n_prev + pi * kM + 4 * s);
        const float4 k4  = *reinterpret_cast<const float4*>(&sk[p][4 * s]);
        const float4 q4  = *reinterpret_cast<const float4*>(&sq[p][4 * s]);

        float4 n4;
        n4.x = fv * np4.x + iv * k4.x;
        n4.y = fv * np4.y + iv * k4.y;
        n4.z = fv * np4.z + iv * k4.z;
        n4.w = fv * np4.w + iv * k4.w;
        *reinterpret_cast<float4*>(out_n + pi * kM + 4 * s) = n4;

        float nq = n4.x * q4.x + n4.y * q4.y + n4.z * q4.z + n4.w * q4.w;
        nq += __shfl_xor(nq, 16, 64);
        nq += __shfl_xor(nq, 8, 64);
        nq += __shfl_xor(nq, 4, 64);
        nq += __shfl_xor(nq, 2, 64);
        nq += __shfl_xor(nq, 1, 64);
        if (s == 0) {
            gi[pi]   = iv;
            gf[pi]   = fv;
            ginv[pi] = 1.f / fmaxf(fabsf(nq), 1.0f);
        }
    }
}

// ---------------------------------------------------------------------------
// Kernel B: C stream — barrier-free (round-11), with PLAIN stores this
// round: out_C (264 MB) nearly fits the 256 MB write-back L3, so a cached
// store rewritten every replay can stay dirty in L3 and never reach HBM.
// (NT stores showed exactly-264MB WRITE_SIZE every round = zero absorption.)
// ---------------------------------------------------------------------------
__global__ __launch_bounds__(kThreads)
void mlstm_stream(const float* __restrict__ C_prev,
                  const float* __restrict__ gq, const float* __restrict__ gk,
                  const float* __restrict__ gv, const float* __restrict__ go,
                  const float* __restrict__ gi, const float* __restrict__ gf,
                  const float* __restrict__ ginv,
                  float* __restrict__ out_C,
                  float* __restrict__ out_ht)
{
    const int pair = blockIdx.x >> 1;
    const int rblk = (blockIdx.x & 1) * kRB;    // row offset: 0 or 64
    const int tid  = threadIdx.x;
    const int r0   = tid >> 5;      // 0..7 (row phase)
    const int s    = tid & 31;      // col group (cols 4s..4s+3)

    const size_t gbase = (size_t)pair * kM;

    // pair-uniform scalars -> s_load
    const float iv  = gi[pair];
    const float fv  = gf[pair];
    const float inv = ginv[pair];

    // per-lane gate vectors (L2-hot)
    const float4 k4 = *reinterpret_cast<const float4*>(gk + gbase + 4 * s);
    const float4 q4 = *reinterpret_cast<const float4*>(gq + gbase + 4 * s);

    // v/o for this thread's 8 rows — uniform within col-group (broadcast)
    float vr[8], orr[8];
    #pragma unroll
    for (int j = 0; j < 8; ++j) {
        vr[j]  = gv[gbase + rblk + r0 + 8 * j];
        orr[j] = go[gbase + rblk + r0 + 8 * j];
    }

    const size_t cbase = (size_t)pair * (kM * kM) + (size_t)rblk * kM;
    const f32x4* cp = reinterpret_cast<const f32x4*>(C_prev + cbase);
    f32x4*       cn = reinterpret_cast<f32x4*>(out_C + cbase);

    // 8 independent C loads in flight
    f32x4 c4[8];
    #pragma unroll
    for (int j = 0; j < 8; ++j)
        c4[j] = cp[tid + kThreads * j];

    float hpart[8];
    #pragma unroll
    for (int j = 0; j < 8; ++j) {
        const float ivr = iv * vr[j];
        f32x4 c_new;
        c_new.x = fv * c4[j].x + ivr * k4.x;
        c_new.y = fv * c4[j].y + ivr * k4.y;
        c_new.z = fv * c4[j].z + ivr * k4.z;
        c_new.w = fv * c4[j].w + ivr * k4.w;
        cn[tid + kThreads * j] = c_new;          // plain store: L3 write-back
        hpart[j] = c_new.x * q4.x + c_new.y * q4.y
                 + c_new.z * q4.z + c_new.w * q4.w;
    }

    // col-group-local reduction: after 5 xors all 32 lanes hold the row sum
    #pragma unroll
    for (int j = 0; j < 8; ++j) {
        hpart[j] += __shfl_xor(hpart[j], 16, 64);
        hpart[j] += __shfl_xor(hpart[j], 8, 64);
        hpart[j] += __shfl_xor(hpart[j], 4, 64);
        hpart[j] += __shfl_xor(hpart[j], 2, 64);
        hpart[j] += __shfl_xor(hpart[j], 1, 64);
    }

    if (s == 0) {
        #pragma unroll
        for (int j = 0; j < 8; ++j) {
            const int row = rblk + r0 + 8 * j;
            out_ht[gbase + row] = orr[j] * hpart[j] * inv;
        }
    }
}

extern "C" void kernel_launch(void* const* d_in, const int* in_sizes, int n_in,
                              void* d_out, int out_size, void* d_ws, size_t ws_size,
                              hipStream_t stream) {
    const float* x      = (const float*)d_in[0];
    const float* C_prev = (const float*)d_in[1];
    const float* n_prev = (const float*)d_in[2];
    const float* Wq = (const float*)d_in[3];
    const float* bq = (const float*)d_in[4];
    const float* Wk = (const float*)d_in[5];
    const float* bk = (const float*)d_in[6];
    const float* Wv = (const float*)d_in[7];
    const float* bv = (const float*)d_in[8];
    const float* wi = (const float*)d_in[9];
    const float* bi = (const float*)d_in[10];
    const float* wf = (const float*)d_in[11];
    const float* bf = (const float*)d_in[12];
    const float* Wo = (const float*)d_in[13];
    const float* bo = (const float*)d_in[14];

    float* out    = (float*)d_out;
    float* out_ht = out;                                    // (T,B,M)
    float* out_C  = out + (size_t)kNPairs * kM;             // (T,B,M,M)
    float* out_n  = out_C + (size_t)kNPairs * kM * kM;      // (T,B,M)

    // workspace layout (floats)
    float* ws = (float*)d_ws;
    const size_t gsz = (size_t)kNPairs * kM;                // 524288
    float* gq   = ws;
    float* gk   = gq + gsz;
    float* gv   = gk + gsz;
    float* go   = gv + gsz;
    float* gi   = go + gsz;
    float* gf   = gi + kNPairs;
    float* ginv = gf + kNPairs;

    mlstm_gates<<<dim3(kNPairs / kGP), dim3(kGateThreads), 0, stream>>>(
        x, n_prev, Wq, bq, Wk, bk, Wv, bv, wi, bi, wf, bf, Wo, bo,
        gq, gk, gv, go, gi, gf, ginv, out_n);

    mlstm_stream<<<dim3(kNPairs * (kM / kRB)), dim3(kThreads), 0, stream>>>(
        C_prev, gq, gk, gv, go, gi, gf, ginv, out_C, out_ht);
}

// Round 13
// 137.094 us; speedup vs baseline: 1.1190x; 1.1190x over previous
//
#include <hip/hip_runtime.h>
#include <math.h>

// Problem constants
constexpr int kT = 512;
constexpr int kB = 8;
constexpr int kD = 512;
constexpr int kM = 128;
constexpr int kNPairs = kT * kB;        // 4096 independent (t,b) pairs
constexpr int kGP = 8;                  // pairs per block (gates kernel)
constexpr int kGateThreads = 512;       // 8 waves: 4 matrices x 2 col-halves
constexpr int kThreads = 256;
constexpr int kRB = 64;                 // rows per stream block (2 blocks/pair)

typedef float f32x4 __attribute__((ext_vector_type(4)));

// ---------------------------------------------------------------------------
// Kernel A: gates — round-10 winner (best known). 512 blocks x 512 threads
// (8 waves), 8 pairs/block. Waves (2m, 2m+1) own matrix m; each wave covers
// 64 of 128 columns (lane -> 1 column, scalar coalesced load + FMA).
// 512 MB weight L2 traffic (weights are L2-resident: 1 MB total),
// 16 waves/CU, no cross-wave reduction. x[p][d] wave-uniform -> s_load.
// ---------------------------------------------------------------------------
__global__ __launch_bounds__(kGateThreads)
void mlstm_gates(const float* __restrict__ x,
                 const float* __restrict__ n_prev,
                 const float* __restrict__ Wq, const float* __restrict__ bq,
                 const float* __restrict__ Wk, const float* __restrict__ bk,
                 const float* __restrict__ Wv, const float* __restrict__ bv,
                 const float* __restrict__ wi, const float* __restrict__ bi,
                 const float* __restrict__ wf, const float* __restrict__ bf,
                 const float* __restrict__ Wo, const float* __restrict__ bo,
                 float* __restrict__ gq, float* __restrict__ gk,
                 float* __restrict__ gv, float* __restrict__ go,
                 float* __restrict__ gi, float* __restrict__ gf,
                 float* __restrict__ ginv,
                 float* __restrict__ out_n)
{
    __shared__ float sq[kGP][kM];     // q (for n-phase)
    __shared__ float sk[kGP][kM];     // k scaled by 1/sqrt(M)
    __shared__ float sif[kGP][2];     // i, f per pair

    const int tid = threadIdx.x;
    const int w   = tid >> 6;         // wave 0..7
    const int m   = w >> 1;           // matrix q,k,v,o
    const int ch  = w & 1;            // column half
    const int l   = tid & 63;         // lane
    const int c   = ch * 64 + l;      // column 0..127
    const int pair_base = blockIdx.x * kGP;
    const float* __restrict__ xblk = x + (size_t)pair_base * kD;

    // ---------------- main matvec: 4 matrices x 2 col-halves ----------------
    {
        const float* __restrict__ Wm = (m == 0) ? Wq : (m == 1) ? Wk : (m == 2) ? Wv : Wo;
        const float* __restrict__ bm = (m == 0) ? bq : (m == 1) ? bk : (m == 2) ? bv : bo;

        float acc[kGP];
        #pragma unroll
        for (int p = 0; p < kGP; ++p) acc[p] = 0.f;

        #pragma unroll 8
        for (int d = 0; d < kD; ++d) {
            const float wv = Wm[(size_t)d * kM + c];    // 256 B/wave, coalesced
            #pragma unroll
            for (int p = 0; p < kGP; ++p) {
                const float xv = xblk[p * kD + d];      // wave-uniform -> s_load
                acc[p] = fmaf(xv, wv, acc[p]);
            }
        }

        const float bc = bm[c];
        const float inv_sqrt_m = 0.08838834764831845f;  // 1/sqrt(128)
        float* __restrict__ gm = (m == 0) ? gq : (m == 1) ? gk : (m == 2) ? gv : go;

        #pragma unroll
        for (int p = 0; p < kGP; ++p) {
            float v = acc[p] + bc;
            if (m == 1) v *= inv_sqrt_m;
            if (m == 3) v = 1.f / (1.f + expf(-v));
            gm[(size_t)(pair_base + p) * kM + c] = v;
            if (m == 0) sq[p][c] = v;
            if (m == 1) sk[p][c] = v;
        }
    }

    // ---------------- i/f gates: wave w handles pair w ----------------------
    {
        const int p = w;                  // pair 0..7
        float ip = 0.f, fp = 0.f;
        #pragma unroll
        for (int dd = 0; dd < kD / 64; ++dd) {
            const int d = l + 64 * dd;
            const float xv = xblk[p * kD + d];
            ip += xv * wi[d];
            fp += xv * wf[d];
        }
        #pragma unroll
        for (int msk = 32; msk >= 1; msk >>= 1) {
            ip += __shfl_xor(ip, msk, 64);
            fp += __shfl_xor(fp, msk, 64);
        }
        if (l == 0) {
            sif[p][0] = expf(ip + bi[0]);
            sif[p][1] = 1.f / (1.f + expf(-(fp + bf[0])));
        }
    }
    __syncthreads();

    // ---------------- n update + normalizer ---------------------------------
    if (tid < 32 * kGP) {
        const int p = tid >> 5;         // pair 0..7 (32 threads per pair)
        const int s = tid & 31;
        const size_t pi = (size_t)(pair_base + p);
        const float iv = sif[p][0];
        const float fv = sif[p][1];

        const float4 np4 = *reinterpret_cast<const float4*>(n_prev + pi * kM + 4 * s);
        const float4 k4  = *reinterpret_cast<const float4*>(&sk[p][4 * s]);
        const float4 q4  = *reinterpret_cast<const float4*>(&sq[p][4 * s]);

        float4 n4;
        n4.x = fv * np4.x + iv * k4.x;
        n4.y = fv * np4.y + iv * k4.y;
        n4.z = fv * np4.z + iv * k4.z;
        n4.w = fv * np4.w + iv * k4.w;
        *reinterpret_cast<float4*>(out_n + pi * kM + 4 * s) = n4;

        float nq = n4.x * q4.x + n4.y * q4.y + n4.z * q4.z + n4.w * q4.w;
        nq += __shfl_xor(nq, 16, 64);
        nq += __shfl_xor(nq, 8, 64);
        nq += __shfl_xor(nq, 4, 64);
        nq += __shfl_xor(nq, 2, 64);
        nq += __shfl_xor(nq, 1, 64);
        if (s == 0) {
            gi[pi]   = iv;
            gf[pi]   = fv;
            ginv[pi] = 1.f / fmaxf(fabsf(nq), 1.0f);
        }
    }
}

// ---------------------------------------------------------------------------
// Kernel B: C stream — round-11 best (barrier-free, NT stores). One block
// per 64-row half of a pair -> 8192 blocks. No LDS, no __syncthreads:
// v/o are col-group-uniform broadcasts, h reduction is col-group-local
// shuffles. Plain loads (L3 retains ~half of C_prev), NT stores (bypass
// L3 so C_prev keeps it — plain stores thrash L3, measured +14 us).
// ---------------------------------------------------------------------------
__global__ __launch_bounds__(kThreads)
void mlstm_stream(const float* __restrict__ C_prev,
                  const float* __restrict__ gq, const float* __restrict__ gk,
                  const float* __restrict__ gv, const float* __restrict__ go,
                  const float* __restrict__ gi, const float* __restrict__ gf,
                  const float* __restrict__ ginv,
                  float* __restrict__ out_C,
                  float* __restrict__ out_ht)
{
    const int pair = blockIdx.x >> 1;
    const int rblk = (blockIdx.x & 1) * kRB;    // row offset: 0 or 64
    const int tid  = threadIdx.x;
    const int r0   = tid >> 5;      // 0..7 (row phase)
    const int s    = tid & 31;      // col group (cols 4s..4s+3)

    const size_t gbase = (size_t)pair * kM;

    // pair-uniform scalars -> s_load
    const float iv  = gi[pair];
    const float fv  = gf[pair];
    const float inv = ginv[pair];

    // per-lane gate vectors (L2-hot)
    const float4 k4 = *reinterpret_cast<const float4*>(gk + gbase + 4 * s);
    const float4 q4 = *reinterpret_cast<const float4*>(gq + gbase + 4 * s);

    // v/o for this thread's 8 rows — uniform within col-group (broadcast)
    float vr[8], orr[8];
    #pragma unroll
    for (int j = 0; j < 8; ++j) {
        vr[j]  = gv[gbase + rblk + r0 + 8 * j];
        orr[j] = go[gbase + rblk + r0 + 8 * j];
    }

    const size_t cbase = (size_t)pair * (kM * kM) + (size_t)rblk * kM;
    const f32x4* cp = reinterpret_cast<const f32x4*>(C_prev + cbase);
    f32x4*       cn = reinterpret_cast<f32x4*>(out_C + cbase);

    // 8 independent C loads in flight
    f32x4 c4[8];
    #pragma unroll
    for (int j = 0; j < 8; ++j)
        c4[j] = cp[tid + kThreads * j];

    float hpart[8];
    #pragma unroll
    for (int j = 0; j < 8; ++j) {
        const float ivr = iv * vr[j];
        f32x4 c_new;
        c_new.x = fv * c4[j].x + ivr * k4.x;
        c_new.y = fv * c4[j].y + ivr * k4.y;
        c_new.z = fv * c4[j].z + ivr * k4.z;
        c_new.w = fv * c4[j].w + ivr * k4.w;
        __builtin_nontemporal_store(c_new, &cn[tid + kThreads * j]);
        hpart[j] = c_new.x * q4.x + c_new.y * q4.y
                 + c_new.z * q4.z + c_new.w * q4.w;
    }

    // col-group-local reduction: after 5 xors all 32 lanes hold the row sum
    #pragma unroll
    for (int j = 0; j < 8; ++j) {
        hpart[j] += __shfl_xor(hpart[j], 16, 64);
        hpart[j] += __shfl_xor(hpart[j], 8, 64);
        hpart[j] += __shfl_xor(hpart[j], 4, 64);
        hpart[j] += __shfl_xor(hpart[j], 2, 64);
        hpart[j] += __shfl_xor(hpart[j], 1, 64);
    }

    if (s == 0) {
        #pragma unroll
        for (int j = 0; j < 8; ++j) {
            const int row = rblk + r0 + 8 * j;
            out_ht[gbase + row] = orr[j] * hpart[j] * inv;
        }
    }
}

extern "C" void kernel_launch(void* const* d_in, const int* in_sizes, int n_in,
                              void* d_out, int out_size, void* d_ws, size_t ws_size,
                              hipStream_t stream) {
    const float* x      = (const float*)d_in[0];
    const float* C_prev = (const float*)d_in[1];
    const float* n_prev = (const float*)d_in[2];
    const float* Wq = (const float*)d_in[3];
    const float* bq = (const float*)d_in[4];
    const float* Wk = (const float*)d_in[5];
    const float* bk = (const float*)d_in[6];
    const float* Wv = (const float*)d_in[7];
    const float* bv = (const float*)d_in[8];
    const float* wi = (const float*)d_in[9];
    const float* bi = (const float*)d_in[10];
    const float* wf = (const float*)d_in[11];
    const float* bf = (const float*)d_in[12];
    const float* Wo = (const float*)d_in[13];
    const float* bo = (const float*)d_in[14];

    float* out    = (float*)d_out;
    float* out_ht = out;                                    // (T,B,M)
    float* out_C  = out + (size_t)kNPairs * kM;             // (T,B,M,M)
    float* out_n  = out_C + (size_t)kNPairs * kM * kM;      // (T,B,M)

    // workspace layout (floats)
    float* ws = (float*)d_ws;
    const size_t gsz = (size_t)kNPairs * kM;                // 524288
    float* gq   = ws;
    float* gk   = gq + gsz;
    float* gv   = gk + gsz;
    float* go   = gv + gsz;
    float* gi   = go + gsz;
    float* gf   = gi + kNPairs;
    float* ginv = gf + kNPairs;

    mlstm_gates<<<dim3(kNPairs / kGP), dim3(kGateThreads), 0, stream>>>(
        x, n_prev, Wq, bq, Wk, bk, Wv, bv, wi, bi, wf, bf, Wo, bo,
        gq, gk, gv, go, gi, gf, ginv, out_n);

    mlstm_stream<<<dim3(kNPairs * (kM / kRB)), dim3(kThreads), 0, stream>>>(
        C_prev, gq, gk, gv, go, gi, gf, ginv, out_C, out_ht);
}